// Round 4
// baseline (169.118 us; speedup 1.0000x reference)
//
#include <hip/hip_runtime.h>
#include <math.h>

// SinusoidalPositionEmbeddings: out[i,j] = sin(t[i]*div(j)) if j even else cos(t[i]*div(j))
// div(j) = exp(-ln(10000) * (j - j%2) / (C-1)),  C = 1024, B = 131072.
// Pure 536.9 MB fp32 write stream. v4 = v3 minus nontemporal stores (A/B):
// nt bypassed L2 write-combining and cost 12% BW. Plain float4 stores.

#define EMBED_C 1024
#define C4 (EMBED_C / 4)      // 256 float4 per row
#define ROWS_PER_BLK 16

__global__ void __launch_bounds__(256)
sinembed_kernel(const float* __restrict__ t, float* __restrict__ out, int nrows) {
    __shared__ float ts[ROWS_PER_BLK];

    const int tid = threadIdx.x;               // 0..255 == col4 index
    const int r0  = blockIdx.x * ROWS_PER_BLK;

    // Stage this block's t-values: one coalesced 64B load by lanes 0..15.
    if (tid < ROWS_PER_BLK) {
        const int r = r0 + tid;
        ts[tid] = (r < nrows) ? t[r] : 0.0f;
    }

    // coef = -log2(10000) / (C-1); div_term = 2^(coef * two_i)
    constexpr float coef = (float)(-13.287712379549449 / 1023.0);
    const int   j0   = tid * 4;                            // even channel base
    const float div0 = exp2f(coef * (float)j0);            // channels j0, j0+1
    const float div1 = exp2f(coef * (float)(j0 + 2));      // channels j0+2, j0+3

    __syncthreads();

    float4* o = reinterpret_cast<float4*>(out) + (size_t)r0 * C4 + tid;

    if (r0 + ROWS_PER_BLK <= nrows) {
        #pragma unroll 4
        for (int row = 0; row < ROWS_PER_BLK; ++row) {
            const float tv = ts[row];          // broadcast LDS read, conflict-free
            float s0, c0, s1, c1;
            __sincosf(tv * div0, &s0, &c0);
            __sincosf(tv * div1, &s1, &c1);
            o[(size_t)row * C4] = make_float4(s0, c0, s1, c1);  // 1024B/wave coalesced
        }
    } else {
        // Tail guard (not hit for B=131072: 131072 % 16 == 0).
        for (int row = 0; row < ROWS_PER_BLK && (r0 + row) < nrows; ++row) {
            const float tv = ts[row];
            float s0, c0, s1, c1;
            __sincosf(tv * div0, &s0, &c0);
            __sincosf(tv * div1, &s1, &c1);
            o[(size_t)row * C4] = make_float4(s0, c0, s1, c1);
        }
    }
}

extern "C" void kernel_launch(void* const* d_in, const int* in_sizes, int n_in,
                              void* d_out, int out_size, void* d_ws, size_t ws_size,
                              hipStream_t stream) {
    const float* t   = (const float*)d_in[0];
    float*       out = (float*)d_out;

    const int nrows = out_size / EMBED_C;                        // 131072
    const int grid  = (nrows + ROWS_PER_BLK - 1) / ROWS_PER_BLK; // 8192 blocks

    sinembed_kernel<<<grid, 256, 0, stream>>>(t, out, nrows);
}

// Round 5
// 88.890 us; speedup vs baseline: 1.9026x; 1.9026x over previous
//
#include <hip/hip_runtime.h>
#include <math.h>

// SinusoidalPositionEmbeddings: out[i,j] = sin(t[i]*div(j)) if j even else cos(t[i]*div(j))
// div(j) = exp(-ln(10000) * (j - j%2) / (C-1)),  C = 1024, B = 131072.
// v5 = round-2 body (best: 97.4us) + chunked XCD swizzle: each XCD gets a
// contiguous 1/8 of rows so its resident blocks write a contiguous sweeping
// ~4MB window (16KB neighbor stride) instead of 128KB-strided set-aliasing
// writes. Mimics the 6.7 TB/s fill kernel's address pattern.

#define EMBED_C 1024
#define C4 (EMBED_C / 4)      // 256 float4 per row
#define ROWS_PER_BLK 4
#define NXCD 8

__global__ void __launch_bounds__(256)
sinembed_kernel(const float* __restrict__ t, float* __restrict__ out, int nrows) {
    // Chunked XCD swizzle (bijective: gridDim.x % 8 == 0 here).
    const int nblk = gridDim.x;
    const int q    = nblk / NXCD;                     // blocks per XCD chunk
    const int bid  = blockIdx.x;
    const int swz  = (bid % NXCD) * q + bid / NXCD;   // XCD (bid%8) owns chunk (bid%8)

    const int tid = threadIdx.x;               // 0..255 == col4 index
    const int r0  = swz * ROWS_PER_BLK;        // first of 4 rows for this block

    // coef = -log2(10000) / (C-1); div_term = 2^(coef * two_i)
    constexpr float coef = (float)(-13.287712379549449 / 1023.0);
    const int   j0   = tid * 4;                            // even channel base
    const float div0 = exp2f(coef * (float)j0);            // channels j0, j0+1
    const float div1 = exp2f(coef * (float)(j0 + 2));      // channels j0+2, j0+3

    float4* o = reinterpret_cast<float4*>(out) + (size_t)r0 * C4 + tid;

    if (r0 + ROWS_PER_BLK <= nrows) {
        // Uniform 16B load (same addr across wave -> broadcast), issued once.
        const float4 tv = *reinterpret_cast<const float4*>(t + r0);
        const float tvals[ROWS_PER_BLK] = {tv.x, tv.y, tv.z, tv.w};

        #pragma unroll
        for (int k = 0; k < ROWS_PER_BLK; ++k) {
            float s0, c0, s1, c1;
            __sincosf(tvals[k] * div0, &s0, &c0);
            __sincosf(tvals[k] * div1, &s1, &c1);
            o[(size_t)k * C4] = make_float4(s0, c0, s1, c1);  // 1024B/wave coalesced
        }
    } else {
        // Tail guard (not hit for B=131072).
        for (int k = 0; k < ROWS_PER_BLK && (r0 + k) < nrows; ++k) {
            const float tvk = t[r0 + k];
            float s0, c0, s1, c1;
            __sincosf(tvk * div0, &s0, &c0);
            __sincosf(tvk * div1, &s1, &c1);
            o[(size_t)k * C4] = make_float4(s0, c0, s1, c1);
        }
    }
}

extern "C" void kernel_launch(void* const* d_in, const int* in_sizes, int n_in,
                              void* d_out, int out_size, void* d_ws, size_t ws_size,
                              hipStream_t stream) {
    const float* t   = (const float*)d_in[0];
    float*       out = (float*)d_out;

    const int nrows = out_size / EMBED_C;                        // 131072
    const int grid  = (nrows + ROWS_PER_BLK - 1) / ROWS_PER_BLK; // 32768 blocks

    sinembed_kernel<<<grid, 256, 0, stream>>>(t, out, nrows);
}